// Round 2
// baseline (1233.304 us; speedup 1.0000x reference)
//
#include <hip/hip_runtime.h>

// Problem constants: flow/flowback [B,2,T,H,W] fp32, masks [B,1,T,H,W] fp32.
#define BB 8
#define CC 2
#define TT 8
#define HH 512
#define WW 512
#define HWSZ (HH * WW)                    // 262144 pixels per (b,t) slice
#define NSLICE (BB * TT)                  // 64 slices
#define TOTAL_ELEMS ((double)(BB * CC * TT) * (double)HWSZ)  // 33,554,432 (mean denom)

// Bilinear sample of a 2-channel image (planes c0,c1; each HxW),
// zeros padding, align_corners=True (pixel-space coords).
__device__ __forceinline__ float2 bilin2(const float* __restrict__ c0,
                                         const float* __restrict__ c1,
                                         float sx, float sy)
{
    float x0f = floorf(sx);
    float y0f = floorf(sy);
    float wx1 = sx - x0f;
    float wy1 = sy - y0f;
    int x0 = (int)x0f;
    int y0 = (int)y0f;
    int x1 = x0 + 1;
    int y1 = y0 + 1;

    float vx0 = (x0 >= 0 && x0 < WW) ? 1.f : 0.f;
    float vx1 = (x1 >= 0 && x1 < WW) ? 1.f : 0.f;
    float vy0 = (y0 >= 0 && y0 < HH) ? 1.f : 0.f;
    float vy1 = (y1 >= 0 && y1 < HH) ? 1.f : 0.f;

    int xc0 = min(max(x0, 0), WW - 1);
    int xc1 = min(max(x1, 0), WW - 1);
    int yc0 = min(max(y0, 0), HH - 1);
    int yc1 = min(max(y1, 0), HH - 1);

    float w00 = (1.f - wx1) * (1.f - wy1) * vx0 * vy0;
    float w10 = wx1         * (1.f - wy1) * vx1 * vy0;
    float w01 = (1.f - wx1) * wy1         * vx0 * vy1;
    float w11 = wx1         * wy1         * vx1 * vy1;

    int o00 = yc0 * WW + xc0;
    int o10 = yc0 * WW + xc1;
    int o01 = yc1 * WW + xc0;
    int o11 = yc1 * WW + xc1;

    float r0 = w00 * c0[o00] + w10 * c0[o10] + w01 * c0[o01] + w11 * c0[o11];
    float r1 = w00 * c1[o00] + w10 * c1[o10] + w01 * c1[o01] + w11 * c1[o11];
    return make_float2(r0, r1);
}

// Grid: 1024 blocks x 256 threads. blockIdx&7 = XCD (dispatch heuristic);
// each XCD owns 8 consecutive slices and its 128 blocks (4/CU, all resident)
// sweep them one at a time -> per-XCD gather working set ~4MB = fits L2.
__global__ __launch_bounds__(256, 4) void flow_loss_kernel(
    const float* __restrict__ flow,
    const float* __restrict__ flowback,
    const float* __restrict__ mask_fw,
    const float* __restrict__ mask_bw,
    double* __restrict__ acc)
{
    const int xcd = blockIdx.x & 7;     // 0..7
    const int o   = blockIdx.x >> 3;    // 0..127: within-XCD block ordinal

    float lsum = 0.f;

    for (int sl = 0; sl < 8; ++sl) {
        const int s = xcd * 8 + sl;     // bt slice 0..63
        const int b = s >> 3;           // T == 8
        const int t = s & 7;

        // [B,C,T,H,W]: plane(b,c,t) offset = ((b*2 + c)*8 + t) * HWSZ
        const float* f0 = flow     + (b * 16 + t) * HWSZ;
        const float* f1 = f0 + 8 * HWSZ;
        const float* g0 = flowback + (b * 16 + t) * HWSZ;
        const float* g1 = g0 + 8 * HWSZ;
        const float* mfp = mask_fw + s * HWSZ;   // [B,1,T,H,W] flat == s*HWSZ+pix
        const float* mbp = mask_bw + s * HWSZ;

#pragma unroll
        for (int gi = 0; gi < 2; ++gi) {
            // 65536 float4-groups per slice; this block covers groups
            // [o*512, o*512+512) = a contiguous 4-row band.
            const int g   = o * 512 + gi * 256 + threadIdx.x;
            const int pix = g * 4;                // 4 | 512 -> never straddles a row
            const int xb  = pix & (WW - 1);
            const int y   = pix >> 9;             // W == 512

            const float4 fxv = *(const float4*)(f0 + pix);
            const float4 fyv = *(const float4*)(f1 + pix);
            const float4 gxv = *(const float4*)(g0 + pix);
            const float4 gyv = *(const float4*)(g1 + pix);
            const float4 mfv = *(const float4*)(mfp + pix);
            const float4 mbv = *(const float4*)(mbp + pix);

            const float fxa[4] = {fxv.x, fxv.y, fxv.z, fxv.w};
            const float fya[4] = {fyv.x, fyv.y, fyv.z, fyv.w};
            const float gxa[4] = {gxv.x, gxv.y, gxv.z, gxv.w};
            const float gya[4] = {gyv.x, gyv.y, gyv.z, gyv.w};
            const float mfa[4] = {mfv.x, mfv.y, mfv.z, mfv.w};
            const float mba[4] = {mbv.x, mbv.y, mbv.z, mbv.w};

#pragma unroll
            for (int k = 0; k < 4; ++k) {
                const float xf = (float)(xb + k);
                const float yf = (float)y;
                // nextloss term: warp(flowback, flow) + flow
                float2 wfb = bilin2(g0, g1, xf + fxa[k], yf + fya[k]);
                // prevloss term: warp(flow, flowback) + flowback
                float2 wf  = bilin2(f0, f1, xf + gxa[k], yf + gya[k]);
                lsum += mfa[k] * (fabsf(wfb.x + fxa[k]) + fabsf(wfb.y + fya[k]))
                      + mba[k] * (fabsf(wf.x  + gxa[k]) + fabsf(wf.y  + gya[k]));
            }
        }
    }

    // wave64 reduce
    for (int off = 32; off > 0; off >>= 1)
        lsum += __shfl_down(lsum, off, 64);

    __shared__ float wsum[4];
    const int lane = threadIdx.x & 63;
    const int wv   = threadIdx.x >> 6;
    if (lane == 0) wsum[wv] = lsum;
    __syncthreads();
    if (threadIdx.x == 0) {
        float ssum = wsum[0] + wsum[1] + wsum[2] + wsum[3];
        atomicAdd(acc, (double)ssum);
    }
}

__global__ void finalize_kernel(const double* __restrict__ acc,
                                const int* __restrict__ npf,
                                float* __restrict__ out)
{
    out[0] = (float)(acc[0] * ((double)npf[0] / TOTAL_ELEMS));
}

extern "C" void kernel_launch(void* const* d_in, const int* in_sizes, int n_in,
                              void* d_out, int out_size, void* d_ws, size_t ws_size,
                              hipStream_t stream)
{
    const float* flow     = (const float*)d_in[0];
    const float* flowback = (const float*)d_in[1];
    const float* mask_fw  = (const float*)d_in[2];
    const float* mask_bw  = (const float*)d_in[3];
    const int*   npf      = (const int*)d_in[4];
    float*  out = (float*)d_out;
    double* acc = (double*)d_ws;

    hipMemsetAsync(d_ws, 0, sizeof(double), stream);

    flow_loss_kernel<<<1024, 256, 0, stream>>>(flow, flowback, mask_fw, mask_bw, acc);
    finalize_kernel<<<1, 1, 0, stream>>>(acc, npf, out);
}

// Round 3
// 890.575 us; speedup vs baseline: 1.3848x; 1.3848x over previous
//
#include <hip/hip_runtime.h>

// Problem constants: flow/flowback [B,2,T,H,W] fp32, masks [B,1,T,H,W] fp32.
#define BB 8
#define CC 2
#define TT 8
#define HH 512
#define WW 512
#define HWSZ (HH * WW)                    // 262144 pixels per (b,t) slice
#define TOTAL_ELEMS ((double)(BB * CC * TT) * (double)HWSZ)  // 33,554,432 (mean denom)

// Unaligned-tolerant 8B load (adjacent x-pair); compiler emits
// global_load_dwordx2 (gfx950 supports 4B-aligned dwordx2).
__device__ __forceinline__ float2 ld2(const float* __restrict__ p) {
    float2 v;
    __builtin_memcpy(&v, p, sizeof(float2));
    return v;
}

// Bilinear sample of a 2-channel image (planes c0,c1; each HxW), zeros
// padding, align_corners=True (pixel-space coords). 4 pair-loads total.
__device__ __forceinline__ void bilin2(const float* __restrict__ c0,
                                       const float* __restrict__ c1,
                                       float sx, float sy,
                                       float& r0, float& r1)
{
    const float x0f = floorf(sx);
    const float y0f = floorf(sy);
    const float wx1 = sx - x0f;
    const float wy1 = sy - y0f;
    const int x0 = (int)x0f;
    const int y0 = (int)y0f;
    const int y1 = y0 + 1;

    // x-pair: load [xl, xl+1] with xl = clamp(x0, 0, W-2).
    const int xl = min(max(x0, 0), WW - 2);
    const float ax = (1.f - wx1) * ((x0 >= 0 && x0 < WW) ? 1.f : 0.f);  // tap x0
    const float bx = wx1 * ((x0 + 1 >= 0 && x0 + 1 < WW) ? 1.f : 0.f);  // tap x0+1
    const bool lo_is_x0 = (x0 == xl);
    // if clamp shifted the window, the valid tap sits on the other element
    const float wl = lo_is_x0 ? ax : bx;
    const float wr = lo_is_x0 ? bx : ax;

    const float wyA = (1.f - wy1) * ((y0 >= 0 && y0 < HH) ? 1.f : 0.f);
    const float wyB = wy1 * ((y1 >= 0 && y1 < HH) ? 1.f : 0.f);
    const int ycA = min(max(y0, 0), HH - 1);
    const int ycB = min(max(y1, 0), HH - 1);
    const int baseA = ycA * WW + xl;
    const int baseB = ycB * WW + xl;

    const float2 a0 = ld2(c0 + baseA);   // row A, channel 0
    const float2 b0 = ld2(c0 + baseB);   // row B, channel 0
    const float2 a1 = ld2(c1 + baseA);   // row A, channel 1
    const float2 b1 = ld2(c1 + baseB);   // row B, channel 1

    r0 = wyA * (wl * a0.x + wr * a0.y) + wyB * (wl * b0.x + wr * b0.y);
    r1 = wyA * (wl * a1.x + wr * a1.y) + wyB * (wl * b1.x + wr * b1.y);
}

// Grid: 2048 blocks x 256 threads. blockIdx&7 = XCD (dispatch heuristic);
// each XCD owns 8 consecutive slices; its 256 blocks sweep one slice at a
// time (each thread = one float4 pixel-group) -> per-XCD working set ~4MB.
__global__ __launch_bounds__(256, 6) void flow_loss_kernel(
    const float* __restrict__ flow,
    const float* __restrict__ flowback,
    const float* __restrict__ mask_fw,
    const float* __restrict__ mask_bw,
    double* __restrict__ acc)
{
    const int xcd = blockIdx.x & 7;     // 0..7
    const int o   = blockIdx.x >> 3;    // 0..255: within-XCD block ordinal

    const int g   = o * 256 + threadIdx.x;  // 0..65535 float4-group in slice
    const int pix = g * 4;                  // 4 | 512 -> never straddles a row
    const int xb  = pix & (WW - 1);
    const int y   = pix >> 9;               // W == 512

    float lsum = 0.f;

    for (int sl = 0; sl < 8; ++sl) {
        const int s = xcd * 8 + sl;     // bt slice 0..63
        const int b = s >> 3;           // T == 8
        const int t = s & 7;

        // [B,C,T,H,W]: plane(b,c,t) offset = ((b*2 + c)*8 + t) * HWSZ
        const float* f0 = flow     + (b * 16 + t) * HWSZ;
        const float* f1 = f0 + 8 * HWSZ;
        const float* g0 = flowback + (b * 16 + t) * HWSZ;
        const float* g1 = g0 + 8 * HWSZ;
        const float* mfp = mask_fw + s * HWSZ;   // [B,1,T,H,W] flat == s*HWSZ+pix
        const float* mbp = mask_bw + s * HWSZ;

        const float4 fxv = *(const float4*)(f0 + pix);
        const float4 fyv = *(const float4*)(f1 + pix);
        const float4 gxv = *(const float4*)(g0 + pix);
        const float4 gyv = *(const float4*)(g1 + pix);
        const float4 mfv = *(const float4*)(mfp + pix);
        const float4 mbv = *(const float4*)(mbp + pix);

        const float fxa[4] = {fxv.x, fxv.y, fxv.z, fxv.w};
        const float fya[4] = {fyv.x, fyv.y, fyv.z, fyv.w};
        const float gxa[4] = {gxv.x, gxv.y, gxv.z, gxv.w};
        const float gya[4] = {gyv.x, gyv.y, gyv.z, gyv.w};
        const float mfa[4] = {mfv.x, mfv.y, mfv.z, mfv.w};
        const float mba[4] = {mbv.x, mbv.y, mbv.z, mbv.w};

#pragma unroll
        for (int k = 0; k < 4; ++k) {
            const float xf = (float)(xb + k);
            const float yf = (float)y;
            float wfbx, wfby, wfx, wfy;
            // nextloss term: warp(flowback, flow) + flow
            bilin2(g0, g1, xf + fxa[k], yf + fya[k], wfbx, wfby);
            // prevloss term: warp(flow, flowback) + flowback
            bilin2(f0, f1, xf + gxa[k], yf + gya[k], wfx, wfy);
            lsum += mfa[k] * (fabsf(wfbx + fxa[k]) + fabsf(wfby + fya[k]))
                  + mba[k] * (fabsf(wfx  + gxa[k]) + fabsf(wfy  + gya[k]));
        }
    }

    // wave64 reduce
    for (int off = 32; off > 0; off >>= 1)
        lsum += __shfl_down(lsum, off, 64);

    __shared__ float wsum[4];
    const int lane = threadIdx.x & 63;
    const int wv   = threadIdx.x >> 6;
    if (lane == 0) wsum[wv] = lsum;
    __syncthreads();
    if (threadIdx.x == 0) {
        float ssum = wsum[0] + wsum[1] + wsum[2] + wsum[3];
        atomicAdd(acc, (double)ssum);
    }
}

__global__ void finalize_kernel(const double* __restrict__ acc,
                                const int* __restrict__ npf,
                                float* __restrict__ out)
{
    out[0] = (float)(acc[0] * ((double)npf[0] / TOTAL_ELEMS));
}

extern "C" void kernel_launch(void* const* d_in, const int* in_sizes, int n_in,
                              void* d_out, int out_size, void* d_ws, size_t ws_size,
                              hipStream_t stream)
{
    const float* flow     = (const float*)d_in[0];
    const float* flowback = (const float*)d_in[1];
    const float* mask_fw  = (const float*)d_in[2];
    const float* mask_bw  = (const float*)d_in[3];
    const int*   npf      = (const int*)d_in[4];
    float*  out = (float*)d_out;
    double* acc = (double*)d_ws;

    hipMemsetAsync(d_ws, 0, sizeof(double), stream);

    flow_loss_kernel<<<2048, 256, 0, stream>>>(flow, flowback, mask_fw, mask_bw, acc);
    finalize_kernel<<<1, 1, 0, stream>>>(acc, npf, out);
}